// Round 7
// baseline (172.005 us; speedup 1.0000x reference)
//
#include <hip/hip_runtime.h>

#define NA 1024
#define NBATCH 4
#define NPAIR 523776           // NA*(NA-1)/2
#define PAIR_TILES 2046        // NPAIR / 256
#define PAIR_BLOCKS 511        // pair blocks, strided tiles {bx, bx+511, ...}
#define GRID_X 512             // 511 pair + 1 atom block; 512*4 = 2048 blocks

#define LOG2E_F 1.44269504088896f
#define LN2_F   0.69314718055995f

// ws layout (byte offsets)
#define WS_MEAN 0              // 8 floats (per-batch mean x,y)
#define WS_W0P  64             // 1024 halves: pair W0eff frags (K=16, x log2e)
#define WS_W0A  2112           // 1024 halves: atom W0eff frags
#define WS_W1P  4160           // 4096 halves: pair W1 frags (phi-permuted rows)
#define WS_W1A  12352          // 4096 halves: atom W1 frags (phi-permuted rows)

typedef _Float16 half4 __attribute__((ext_vector_type(4)));
typedef _Float16 half8 __attribute__((ext_vector_type(8)));
typedef float float4v __attribute__((ext_vector_type(4)));

#if defined(__has_builtin)
#  if __has_builtin(__builtin_amdgcn_exp2f)
#    define EXP2F(x) __builtin_amdgcn_exp2f(x)
#  endif
#endif
#ifndef EXP2F
#  define EXP2F(x) exp2f(x)
#endif

// y = log2e * z.  sig4(y) = 1/(1+exp2(-y)) = sigmoid(z), elementwise on 4.
// Vector form so the non-trans ops lower to v_pk_add_f32 / v_pk_mul_f32 /
// v_pk_fma_f32 (packed fp32, 2 elems per issue) — trans ops stay scalar.
__device__ __forceinline__ float4v sig4(float4v y) {
    float4v e;
#pragma unroll
    for (int r = 0; r < 4; r++) e[r] = EXP2F(-y[r]);   // negate = free src mod
    float4v d = e + 1.0f;                              // v_pk_add_f32 x2
    float4v rr;
#pragma unroll
    for (int r = 0; r < 4; r++) rr[r] = __builtin_amdgcn_rcpf(d[r]);
    return rr;
}

__device__ __forceinline__ uint32_t pkf16(float a, float b) {
    union { _Float16 h[2]; uint32_t u; } x;
    x.h[0] = (_Float16)a; x.h[1] = (_Float16)b;   // RTNE
    return x.u;
}

// ---------------------------------------------------------------------------
// prep: blocks 0..3 -> per-batch mean + out[b] init; block 4 -> weight packing.
// W0eff (K=16, scaled by log2e): rows 0..4 = raw features, 5 = b0 (feature
// slot 5 == 1.0), 6..9 = one-hot(i) rows (embed@W0 folded), 10..13 =
// one-hot(j) rows (pair only), 14..15 = 0.
// K=16 frag order: [(nt*64+lane)*4 + j] = W[(lane>>4)*4+j][nt*16+(lane&15)]
//
// W1 frags phi-permuted so transposed-L0 output regs ARE the L1 B-fragment:
//   phi(ks*32+8q+j) = ks*32 + (j<4 ? 4q+j : 16+4q+j-4).
// W1 itself is NOT rescaled (ln2*log2e = 1); b1 gets *log2e at load; W2 *ln2.
// ---------------------------------------------------------------------------
__global__ void prep_kernel(const float* __restrict__ positions,
                            const float* __restrict__ embed,
                            const float* __restrict__ aW0,
                            const float* __restrict__ ab0,
                            const float* __restrict__ aW1,
                            const float* __restrict__ ab2,
                            const float* __restrict__ pW0,
                            const float* __restrict__ pb0,
                            const float* __restrict__ pW1,
                            const float* __restrict__ pb2,
                            char* __restrict__ ws,
                            float* __restrict__ out) {
    const int tid = threadIdx.x;
    if (blockIdx.x < 4) {
        const int b = blockIdx.x;
        const float2* pos = (const float2*)positions + b * NA;
        float sx = 0.f, sy = 0.f;
        for (int t = tid; t < NA; t += 256) {
            float2 p = pos[t];
            sx += p.x; sy += p.y;
        }
#pragma unroll
        for (int off = 32; off > 0; off >>= 1) {
            sx += __shfl_down(sx, off);
            sy += __shfl_down(sy, off);
        }
        __shared__ float rxs[4], rys[4];
        const int w = tid >> 6, lane = tid & 63;
        if (lane == 0) { rxs[w] = sx; rys[w] = sy; }
        __syncthreads();
        if (tid == 0) {
            float* meanws = (float*)(ws + WS_MEAN);
            meanws[b * 2 + 0] = (rxs[0] + rxs[1] + rxs[2] + rxs[3]) * (1.f / NA);
            meanws[b * 2 + 1] = (rys[0] + rys[1] + rys[2] + rys[3]) * (1.f / NA);
            out[b] = (float)NPAIR * pb2[0] + (float)NA * ab2[0];
        }
        return;
    }

    // ---- weight fragment packing ----
    _Float16* w0p = (_Float16*)(ws + WS_W0P);
    _Float16* w0a = (_Float16*)(ws + WS_W0A);
    _Float16* w1p = (_Float16*)(ws + WS_W1P);
    _Float16* w1a = (_Float16*)(ws + WS_W1A);

    for (int idx = tid; idx < 1024; idx += 256) {
        const int j = idx & 3, lane = (idx >> 2) & 63, nt = idx >> 8;
        const int k = ((lane >> 4) << 2) + j;      // 4q + j, 0..15
        const int col = nt * 16 + (lane & 15);
        float vp = 0.f, va = 0.f;
        if (k < 5) {
            vp = pW0[k * 64 + col];
            va = aW0[k * 64 + col];
        } else if (k == 5) {               // bias row (feature slot 5 == 1.0)
            vp = pb0[col];
            va = ab0[col];
        } else if (k >= 6 && k <= 9) {
            const int s = k - 6;
            float accp = 0.f, acca = 0.f;
#pragma unroll
            for (int e = 0; e < 16; e++) {
                float em = embed[s * 16 + e];
                accp += em * pW0[(5 + e) * 64 + col];
                acca += em * aW0[(5 + e) * 64 + col];
            }
            vp = accp; va = acca;
        } else if (k >= 10 && k <= 13) {
            const int s = k - 10;
            float accp = 0.f;
#pragma unroll
            for (int e = 0; e < 16; e++)
                accp += embed[s * 16 + e] * pW0[(21 + e) * 64 + col];
            vp = accp; va = 0.f;
        }
        w0p[idx] = (_Float16)(vp * LOG2E_F);
        w0a[idx] = (_Float16)(va * LOG2E_F);
    }
    for (int idx = tid; idx < 4096; idx += 256) {
        const int j = idx & 7, lane = (idx >> 3) & 63;
        const int ks = (idx >> 9) & 1, nt = idx >> 10;
        const int q = lane >> 4;
        // phi row permutation: slot (q,j) sources hidden 4q+j (j<4) / 16+4q+j-4
        const int m = (j < 4) ? (4 * q + j) : (16 + 4 * q + (j - 4));
        const int k = ks * 32 + m;
        const int col = nt * 16 + (lane & 15);
        w1p[idx] = (_Float16)pW1[k * 64 + col];
        w1a[idx] = (_Float16)aW1[k * 64 + col];
    }
}

// ---------------------------------------------------------------------------
// fused pair+atom MLP, transposed dataflow, log2e-folded silu chain, and a
// software-pipelined feature stage:
//   per tile t: issue t+1's decode+gathers BEFORE mt0/mt1 (VMEM hides under
//   ~1.5k cyc of compute); pack+LDS-write t+1 after mt1; stagger the 4 xfr
//   ds_reads (2 after the write, 1 after mt2, 1 after mt3) so each read
//   issues >= 1 MTBODY before first use. Old xfr values are in regs, so the
//   early LDS overwrite is safe (same-wave DS ordering).
// Pair (i,j) decode is exact closed-form (no correction loops): D < 2^22 is
// f32-exact, sqrt correctly rounded; boundary p's have D a perfect square
// (exact), off-boundary margin >= 2/2047 >> 1e-4 float error.
// h-pack uses scalar RTNE element inserts (R3 form) — the cvt_pkrtz vector
// pack forms (union AND shufflevector) both produced a ~12 B/thread scratch
// alloca (6.2 MB WRITE_SIZE, R5/R6).
// __launch_bounds__(256,4): no-spill codegen, 64 VGPR = 8 waves/SIMD.
// ---------------------------------------------------------------------------
__global__ __launch_bounds__(256, 4) void mlp_kernel(
    const float* __restrict__ positions,
    const int*   __restrict__ species,
    const float* __restrict__ efield,
    const float* __restrict__ ab1, const float* __restrict__ aW2,
    const float* __restrict__ pb1, const float* __restrict__ pW2,
    const char*  __restrict__ ws,
    float* __restrict__ out)
{
    const int b    = blockIdx.y;
    const int bx   = blockIdx.x;
    const bool is_atom = (bx == PAIR_BLOCKS);
    const int tid  = threadIdx.x;
    const int lane = tid & 63;
    const int wv   = tid >> 6;
    const int n16  = lane & 15;
    const int quad = lane >> 4;

    // X staging: 64 rows x 24 halves per wave (cols 0..15 live, 16..23 pad).
    // 48B row stride: conflict-free for both b128 writes and b64 reads.
    __shared__ __attribute__((aligned(16))) _Float16 Xbuf[4][64][24];
    _Float16 (*rows)[24] = Xbuf[wv];

    // ---- block-wide weight fragments (coalesced, once per block) ----
    const _Float16* w0w = (const _Float16*)(ws + (is_atom ? WS_W0A : WS_W0P));
    const _Float16* w1w = (const _Float16*)(ws + (is_atom ? WS_W1A : WS_W1P));
    half4 w0f[4];
    half8 w1f[4][2];
#pragma unroll
    for (int nt = 0; nt < 4; nt++)
        w0f[nt] = *(const half4*)(w0w + (nt * 64 + lane) * 4);
#pragma unroll
    for (int nt = 0; nt < 4; nt++)
#pragma unroll
        for (int ks = 0; ks < 2; ks++)
            w1f[nt][ks] = *(const half8*)(w1w + ((nt * 2 + ks) * 64 + lane) * 8);

    const float* B1 = is_atom ? ab1 : pb1;
    float4v b1q[4];
#pragma unroll
    for (int nt = 0; nt < 4; nt++) {
        float4v t4 = *(const float4v*)(B1 + nt * 16 + quad * 4);  // rows quad*4+r
        b1q[nt] = t4 * LOG2E_F;
    }

    const float Ex = efield[b * 2 + 0];
    const float Ey = efield[b * 2 + 1];
    const float enorm = sqrtf(Ex * Ex + Ey * Ey);
    const float* meanws = (const float*)(ws + WS_MEAN);
    const float mnx = meanws[b * 2 + 0];
    const float mny = meanws[b * 2 + 1];

    const float2* pos = (const float2*)positions + b * NA;
    const int*    spc = species + b * NA;

    // loop-invariant feature words
    const uint32_t enorm_pack = pkf16(enorm, 1.0f);   // halves 4,5 (enorm, bias)
    const uint32_t ef_pack    = pkf16(Ex, Ey);        // atom halves 2,3

    // blocks 0,1 take a 5th tile (2046 = 511*4 + 2)
    const int my_tiles = is_atom ? 4 : ((bx < PAIR_TILES - 4 * PAIR_BLOCKS) ? 5 : 4);

    const float4v zero4 = {0.f, 0.f, 0.f, 0.f};
    float4v acce[4];
#pragma unroll
    for (int nt = 0; nt < 4; nt++) acce[nt] = zero4;

    half4 xfr[4];          // constant-indexed only (macros use literal MT)

// ---- staging macros (named scalars only — no aggregates, no scratch) ----
#define LOADRAW(TT, o_pi, o_pj, o_si, o_sj) do {                              \
        if (!is_atom) {                                                       \
            const int p_ = (bx + (TT) * PAIR_BLOCKS) * 256 + tid;             \
            const float sq_ = sqrtf((float)(2047 * 2047 - 8 * p_));           \
            int i_ = (int)((2047.0f - sq_) * 0.5f);                           \
            i_ = i_ < 0 ? 0 : (i_ > 1022 ? 1022 : i_);                        \
            const int j_ = p_ - ((i_ * (2047 - i_)) >> 1) + i_ + 1;           \
            o_pi = pos[i_]; o_pj = pos[j_];                                   \
            o_si = spc[i_]; o_sj = spc[j_];                                   \
        } else {                                                              \
            const int n_ = (TT) * 256 + tid;                                  \
            o_pi = pos[n_]; o_si = spc[n_];                                   \
        }                                                                     \
    } while (0)

#define PACKWRITE(i_pi, i_pj, i_si, i_sj) do {                                \
        uint32_t w01_, w23_; uint64_t ohi_, ohj_;                             \
        if (!is_atom) {                                                       \
            float f0_ = i_pi.x - i_pj.x, f1_ = i_pi.y - i_pj.y;               \
            float f2_ = sqrtf(f0_ * f0_ + f1_ * f1_);                         \
            float inv_ = __builtin_amdgcn_rcpf(fmaxf(f2_, 1e-12f));           \
            float f3_ = (Ex * f0_ + Ey * f1_) * inv_;                         \
            w01_ = pkf16(f0_, f1_); w23_ = pkf16(f2_, f3_);                   \
            ohi_ = 0x3C00ull << (i_si * 16);                                  \
            ohj_ = 0x3C00ull << (i_sj * 16);                                  \
        } else {                                                              \
            w01_ = pkf16(i_pi.x - mnx, i_pi.y - mny);                         \
            w23_ = ef_pack;                                                   \
            ohi_ = 0x3C00ull << (i_si * 16);                                  \
            ohj_ = 0;                                                         \
        }                                                                     \
        int4* dst_ = (int4*)&rows[lane][0];                                   \
        int4 lo_, hi_;                                                        \
        lo_.x = (int)w01_; lo_.y = (int)w23_;                                 \
        lo_.z = (int)enorm_pack; lo_.w = (int)(uint32_t)ohi_;                 \
        hi_.x = (int)(uint32_t)(ohi_ >> 32); hi_.y = (int)(uint32_t)ohj_;     \
        hi_.z = (int)(uint32_t)(ohj_ >> 32); hi_.w = 0;                       \
        dst_[0] = lo_; dst_[1] = hi_;                                         \
    } while (0)

#define READXFR_ONE(MT)                                                       \
    xfr[MT] = *(const half4*)(&rows[(MT) * 16 + n16][quad * 4])

#define MTBODY(MT) do {                                                       \
        float4v acc_[4];                                                      \
        _Pragma("unroll")                                                     \
        for (int nt = 0; nt < 4; nt++)                                        \
            acc_[nt] = __builtin_amdgcn_mfma_f32_16x16x16f16(                 \
                w0f[nt], xfr[MT], zero4, 0, 0, 0);                            \
        float4v s0_ = acc_[0] * sig4(acc_[0]);                                \
        float4v s1_ = acc_[1] * sig4(acc_[1]);                                \
        float4v s2_ = acc_[2] * sig4(acc_[2]);                                \
        float4v s3_ = acc_[3] * sig4(acc_[3]);                                \
        half8 h0_, h1_;                                                       \
        _Pragma("unroll")                                                     \
        for (int r = 0; r < 4; r++) {                                         \
            h0_[r]     = (_Float16)s0_[r];                                    \
            h0_[4 + r] = (_Float16)s1_[r];                                    \
            h1_[r]     = (_Float16)s2_[r];                                    \
            h1_[4 + r] = (_Float16)s3_[r];                                    \
        }                                                                     \
        _Pragma("unroll")                                                     \
        for (int nt = 0; nt < 4; nt++) {                                      \
            float4v c_ = b1q[nt];                                             \
            c_ = __builtin_amdgcn_mfma_f32_16x16x32_f16(w1f[nt][0], h0_, c_, 0, 0, 0); \
            c_ = __builtin_amdgcn_mfma_f32_16x16x32_f16(w1f[nt][1], h1_, c_, 0, 0, 0); \
            acce[nt] += c_ * sig4(c_);                                        \
        }                                                                     \
    } while (0)

    // ---- prologue: tile 0 through the serial path once ----
    {
        float2 c_pi, c_pj; int c_si = 0, c_sj = 0;
        LOADRAW(0, c_pi, c_pj, c_si, c_sj);
        PACKWRITE(c_pi, c_pj, c_si, c_sj);
        READXFR_ONE(0); READXFR_ONE(1); READXFR_ONE(2); READXFR_ONE(3);
    }

    for (int t = 0; t < my_tiles; ++t) {
        const bool have_next = (t + 1 < my_tiles);
        float2 n_pi, n_pj; int n_si = 0, n_sj = 0;
        if (have_next) LOADRAW(t + 1, n_pi, n_pj, n_si, n_sj);   // VMEM in flight

        MTBODY(0);
        MTBODY(1);
        if (have_next) {
            PACKWRITE(n_pi, n_pj, n_si, n_sj);   // loads landed under mt0/mt1
            READXFR_ONE(0); READXFR_ONE(1);      // next xfr[0,1]; old ones consumed
        }
        MTBODY(2);
        if (have_next) READXFR_ONE(2);
        MTBODY(3);
        if (have_next) READXFR_ONE(3);
    }

#undef LOADRAW
#undef PACKWRITE
#undef READXFR_ONE
#undef MTBODY

    // ---- deferred W2 dot (W2 only live after the loop), *ln2 once ----
    const float* W2 = is_atom ? aW2 : pW2;
    float4v dot4 = {0.f, 0.f, 0.f, 0.f};
#pragma unroll
    for (int nt = 0; nt < 4; nt++) {
        float4v w2v4 = *(const float4v*)(W2 + nt * 16 + quad * 4);
        dot4 += acce[nt] * w2v4;
    }
    float energy = (dot4[0] + dot4[1] + dot4[2] + dot4[3]) * LN2_F;

    // ---- block reduction -> one atomicAdd per block ----
#pragma unroll
    for (int off = 32; off > 0; off >>= 1)
        energy += __shfl_down(energy, off);
    __shared__ float wsum[4];
    if (lane == 0) wsum[wv] = energy;
    __syncthreads();
    if (tid == 0)
        atomicAdd(&out[b], wsum[0] + wsum[1] + wsum[2] + wsum[3]);
}

// ---------------------------------------------------------------------------
extern "C" void kernel_launch(void* const* d_in, const int* in_sizes, int n_in,
                              void* d_out, int out_size, void* d_ws, size_t ws_size,
                              hipStream_t stream) {
    const float* positions = (const float*)d_in[0];
    const int*   species   = (const int*)  d_in[1];
    const float* efield    = (const float*)d_in[2];
    const float* embed     = (const float*)d_in[3];
    const float* aW0 = (const float*)d_in[4];
    const float* ab0 = (const float*)d_in[5];
    const float* aW1 = (const float*)d_in[6];
    const float* ab1 = (const float*)d_in[7];
    const float* aW2 = (const float*)d_in[8];
    const float* ab2 = (const float*)d_in[9];
    const float* pW0 = (const float*)d_in[10];
    const float* pb0 = (const float*)d_in[11];
    const float* pW1 = (const float*)d_in[12];
    const float* pb1 = (const float*)d_in[13];
    const float* pW2 = (const float*)d_in[14];
    const float* pb2 = (const float*)d_in[15];
    float* outp = (float*)d_out;
    char*  ws   = (char*)d_ws;

    prep_kernel<<<dim3(5), dim3(256), 0, stream>>>(
        positions, embed, aW0, ab0, aW1, ab2, pW0, pb0, pW1, pb2, ws, outp);
    mlp_kernel<<<dim3(GRID_X, NBATCH), dim3(256), 0, stream>>>(
        positions, species, efield,
        ab1, aW2, pb1, pW2,
        ws, outp);
}

// Round 8
// 153.172 us; speedup vs baseline: 1.1230x; 1.1230x over previous
//
#include <hip/hip_runtime.h>

#define NA 1024
#define NBATCH 4
#define NPAIR 523776           // NA*(NA-1)/2
#define PAIR_TILES 2046        // NPAIR / 256
#define PAIR_BLOCKS 511        // pair blocks, strided tiles {bx, bx+511, ...}
#define GRID_X 512             // 511 pair + 1 atom block; 512*4 = 2048 blocks

#define LOG2E_F 1.44269504088896f
#define LN2_F   0.69314718055995f

// ws layout (byte offsets)
#define WS_MEAN 0              // 8 floats (per-batch mean x,y)
#define WS_W0P  64             // 1024 halves: pair W0eff frags (K=16, x log2e)
#define WS_W0A  2112           // 1024 halves: atom W0eff frags
#define WS_W1P  4160           // 4096 halves: pair W1 frags (phi-permuted rows)
#define WS_W1A  12352          // 4096 halves: atom W1 frags (phi-permuted rows)

typedef _Float16 half4 __attribute__((ext_vector_type(4)));
typedef _Float16 half8 __attribute__((ext_vector_type(8)));
typedef float float4v __attribute__((ext_vector_type(4)));

#if defined(__has_builtin)
#  if __has_builtin(__builtin_amdgcn_exp2f)
#    define EXP2F(x) __builtin_amdgcn_exp2f(x)
#  endif
#endif
#ifndef EXP2F
#  define EXP2F(x) exp2f(x)
#endif

// y = log2e * z.  sig4(y) = 1/(1+exp2(-y)) = sigmoid(z), elementwise on 4.
// Vector form so the non-trans ops lower to v_pk_add_f32 / v_pk_mul_f32 /
// v_pk_fma_f32 (packed fp32, 2 elems per issue) — trans ops stay scalar.
__device__ __forceinline__ float4v sig4(float4v y) {
    float4v e;
#pragma unroll
    for (int r = 0; r < 4; r++) e[r] = EXP2F(-y[r]);   // negate = free src mod
    float4v d = e + 1.0f;                              // v_pk_add_f32 x2
    float4v rr;
#pragma unroll
    for (int r = 0; r < 4; r++) rr[r] = __builtin_amdgcn_rcpf(d[r]);
    return rr;
}

__device__ __forceinline__ uint32_t pkf16(float a, float b) {
    union { _Float16 h[2]; uint32_t u; } x;
    x.h[0] = (_Float16)a; x.h[1] = (_Float16)b;   // RTNE
    return x.u;
}

// ---------------------------------------------------------------------------
// prep: blocks 0..3 -> per-batch mean + out[b] init; block 4 -> weight packing.
// W0eff (K=16, scaled by log2e): rows 0..4 = raw features, 5 = b0 (feature
// slot 5 == 1.0), 6..9 = one-hot(i) rows (embed@W0 folded), 10..13 =
// one-hot(j) rows (pair only), 14..15 = 0.
// K=16 frag order: [(nt*64+lane)*4 + j] = W[(lane>>4)*4+j][nt*16+(lane&15)]
//
// W1 frags phi-permuted so transposed-L0 output regs ARE the L1 B-fragment:
//   phi(ks*32+8q+j) = ks*32 + (j<4 ? 4q+j : 16+4q+j-4).
// W1 itself is NOT rescaled (ln2*log2e = 1); b1 gets *log2e at load; W2 *ln2.
// ---------------------------------------------------------------------------
__global__ void prep_kernel(const float* __restrict__ positions,
                            const float* __restrict__ embed,
                            const float* __restrict__ aW0,
                            const float* __restrict__ ab0,
                            const float* __restrict__ aW1,
                            const float* __restrict__ ab2,
                            const float* __restrict__ pW0,
                            const float* __restrict__ pb0,
                            const float* __restrict__ pW1,
                            const float* __restrict__ pb2,
                            char* __restrict__ ws,
                            float* __restrict__ out) {
    const int tid = threadIdx.x;
    if (blockIdx.x < 4) {
        const int b = blockIdx.x;
        const float2* pos = (const float2*)positions + b * NA;
        float sx = 0.f, sy = 0.f;
        for (int t = tid; t < NA; t += 256) {
            float2 p = pos[t];
            sx += p.x; sy += p.y;
        }
#pragma unroll
        for (int off = 32; off > 0; off >>= 1) {
            sx += __shfl_down(sx, off);
            sy += __shfl_down(sy, off);
        }
        __shared__ float rxs[4], rys[4];
        const int w = tid >> 6, lane = tid & 63;
        if (lane == 0) { rxs[w] = sx; rys[w] = sy; }
        __syncthreads();
        if (tid == 0) {
            float* meanws = (float*)(ws + WS_MEAN);
            meanws[b * 2 + 0] = (rxs[0] + rxs[1] + rxs[2] + rxs[3]) * (1.f / NA);
            meanws[b * 2 + 1] = (rys[0] + rys[1] + rys[2] + rys[3]) * (1.f / NA);
            out[b] = (float)NPAIR * pb2[0] + (float)NA * ab2[0];
        }
        return;
    }

    // ---- weight fragment packing ----
    _Float16* w0p = (_Float16*)(ws + WS_W0P);
    _Float16* w0a = (_Float16*)(ws + WS_W0A);
    _Float16* w1p = (_Float16*)(ws + WS_W1P);
    _Float16* w1a = (_Float16*)(ws + WS_W1A);

    for (int idx = tid; idx < 1024; idx += 256) {
        const int j = idx & 3, lane = (idx >> 2) & 63, nt = idx >> 8;
        const int k = ((lane >> 4) << 2) + j;      // 4q + j, 0..15
        const int col = nt * 16 + (lane & 15);
        float vp = 0.f, va = 0.f;
        if (k < 5) {
            vp = pW0[k * 64 + col];
            va = aW0[k * 64 + col];
        } else if (k == 5) {               // bias row (feature slot 5 == 1.0)
            vp = pb0[col];
            va = ab0[col];
        } else if (k >= 6 && k <= 9) {
            const int s = k - 6;
            float accp = 0.f, acca = 0.f;
#pragma unroll
            for (int e = 0; e < 16; e++) {
                float em = embed[s * 16 + e];
                accp += em * pW0[(5 + e) * 64 + col];
                acca += em * aW0[(5 + e) * 64 + col];
            }
            vp = accp; va = acca;
        } else if (k >= 10 && k <= 13) {
            const int s = k - 10;
            float accp = 0.f;
#pragma unroll
            for (int e = 0; e < 16; e++)
                accp += embed[s * 16 + e] * pW0[(21 + e) * 64 + col];
            vp = accp; va = 0.f;
        }
        w0p[idx] = (_Float16)(vp * LOG2E_F);
        w0a[idx] = (_Float16)(va * LOG2E_F);
    }
    for (int idx = tid; idx < 4096; idx += 256) {
        const int j = idx & 7, lane = (idx >> 3) & 63;
        const int ks = (idx >> 9) & 1, nt = idx >> 10;
        const int q = lane >> 4;
        // phi row permutation: slot (q,j) sources hidden 4q+j (j<4) / 16+4q+j-4
        const int m = (j < 4) ? (4 * q + j) : (16 + 4 * q + (j - 4));
        const int k = ks * 32 + m;
        const int col = nt * 16 + (lane & 15);
        w1p[idx] = (_Float16)pW1[k * 64 + col];
        w1a[idx] = (_Float16)aW1[k * 64 + col];
    }
}

// ---------------------------------------------------------------------------
// fused pair+atom MLP, transposed dataflow, log2e-folded silu chain:
//   L0 (K=16): acc = mfma_16x16x16(W0frag, Xfrag) -> y0 = log2e*z0
//   h' = y0*sig4(y0) = log2e*silu(z0), packed with scalar RTNE element
//   inserts (the ONLY pack form with proven no-scratch codegen — cvt_pkrtz
//   via union or shufflevector both produced a per-thread alloca, R5/R6;
//   pipelining extra live state across the mt-loop spilled too, R7).
//   L1 (K=64): c = mfma_16x16x32(W1frag, h) + b1*log2e -> y1 = log2e*z1
//   acce += c*sig4(c) (v_pk_fma); after the t-loop: energy = ln2*dot(acce,W2).
// Pair (i,j) decode is exact closed-form (no correction loops): D < 2^22 is
// f32-exact, sqrt correctly rounded; boundary p's have D a perfect square
// (exact), off-boundary margin >= 2/2047 >> 1e-4 float error.
// __launch_bounds__(256,4): no-spill codegen, 64 VGPR = 8 waves/SIMD.
// ---------------------------------------------------------------------------
__global__ __launch_bounds__(256, 4) void mlp_kernel(
    const float* __restrict__ positions,
    const int*   __restrict__ species,
    const float* __restrict__ efield,
    const float* __restrict__ ab1, const float* __restrict__ aW2,
    const float* __restrict__ pb1, const float* __restrict__ pW2,
    const char*  __restrict__ ws,
    float* __restrict__ out)
{
    const int b    = blockIdx.y;
    const int bx   = blockIdx.x;
    const bool is_atom = (bx == PAIR_BLOCKS);
    const int tid  = threadIdx.x;
    const int lane = tid & 63;
    const int wv   = tid >> 6;
    const int n16  = lane & 15;
    const int quad = lane >> 4;

    // X staging: 64 rows x 24 halves per wave (cols 0..15 live, 16..23 pad).
    // 48B row stride: conflict-free for both b128 writes and b64 reads.
    __shared__ __attribute__((aligned(16))) _Float16 Xbuf[4][64][24];
    _Float16 (*rows)[24] = Xbuf[wv];

    // ---- block-wide weight fragments (coalesced, once per block) ----
    const _Float16* w0w = (const _Float16*)(ws + (is_atom ? WS_W0A : WS_W0P));
    const _Float16* w1w = (const _Float16*)(ws + (is_atom ? WS_W1A : WS_W1P));
    half4 w0f[4];
    half8 w1f[4][2];
#pragma unroll
    for (int nt = 0; nt < 4; nt++)
        w0f[nt] = *(const half4*)(w0w + (nt * 64 + lane) * 4);
#pragma unroll
    for (int nt = 0; nt < 4; nt++)
#pragma unroll
        for (int ks = 0; ks < 2; ks++)
            w1f[nt][ks] = *(const half8*)(w1w + ((nt * 2 + ks) * 64 + lane) * 8);

    const float* B1 = is_atom ? ab1 : pb1;
    float4v b1q[4];
#pragma unroll
    for (int nt = 0; nt < 4; nt++) {
        float4v t4 = *(const float4v*)(B1 + nt * 16 + quad * 4);  // rows quad*4+r
        b1q[nt] = t4 * LOG2E_F;
    }

    const float Ex = efield[b * 2 + 0];
    const float Ey = efield[b * 2 + 1];
    const float enorm = sqrtf(Ex * Ex + Ey * Ey);
    const float* meanws = (const float*)(ws + WS_MEAN);
    const float mnx = meanws[b * 2 + 0];
    const float mny = meanws[b * 2 + 1];

    // loop-invariant feature words
    const uint32_t enorm_pack = pkf16(enorm, 1.0f);   // halves 4,5 (enorm, bias)
    const uint32_t ef_pack    = pkf16(Ex, Ey);        // atom halves 2,3

    // blocks 0,1 take a 5th tile (2046 = 511*4 + 2)
    const int my_tiles = is_atom ? 4 : ((bx < PAIR_TILES - 4 * PAIR_BLOCKS) ? 5 : 4);

    const float4v zero4 = {0.f, 0.f, 0.f, 0.f};
    float4v acce[4];
#pragma unroll
    for (int nt = 0; nt < 4; nt++) acce[nt] = zero4;

    for (int t = 0; t < my_tiles; ++t) {
        // ---- build feature row (14 live halves of K=16, slot5 = 1.0) ----
        uint32_t w01, w23;
        uint64_t ohi, ohj;
        if (!is_atom) {
            const int tile = bx + t * PAIR_BLOCKS;
            const int p = tile * 256 + tid;
            // exact closed-form triangular decode (see header comment)
            const float s = sqrtf((float)(2047 * 2047 - 8 * p));
            int i = (int)((2047.0f - s) * 0.5f);
            i = i < 0 ? 0 : (i > 1022 ? 1022 : i);
            const int j = p - ((i * (2047 - i)) >> 1) + i + 1;
            const float2* pos = (const float2*)positions + b * NA;
            float2 pi = pos[i], pj = pos[j];
            float f0 = pi.x - pj.x, f1 = pi.y - pj.y;     // mean cancels
            float f2 = sqrtf(f0 * f0 + f1 * f1);
            float inv = __builtin_amdgcn_rcpf(fmaxf(f2, 1e-12f));
            float f3 = (Ex * f0 + Ey * f1) * inv;
            w01 = pkf16(f0, f1);
            w23 = pkf16(f2, f3);
            ohi = 0x3C00ull << (species[b * NA + i] * 16);
            ohj = 0x3C00ull << (species[b * NA + j] * 16);
        } else {
            const int n = t * 256 + tid;
            float2 pn = ((const float2*)positions)[b * NA + n];
            w01 = pkf16(pn.x - mnx, pn.y - mny);
            w23 = ef_pack;
            ohi = 0x3C00ull << (species[b * NA + n] * 16);
            ohj = 0;
        }
        // halves: 0..4 = f0..f4(enorm), 5 = 1.0 (bias), 6..9 = oh_i, 10..13 = oh_j
        int4* dst = (int4*)&rows[lane][0];
        int4 lo, hi;
        lo.x = (int)w01;
        lo.y = (int)w23;
        lo.z = (int)enorm_pack;
        lo.w = (int)(uint32_t)ohi;
        hi.x = (int)(uint32_t)(ohi >> 32);
        hi.y = (int)(uint32_t)ohj;
        hi.z = (int)(uint32_t)(ohj >> 32);
        hi.w = 0;
        dst[0] = lo;
        dst[1] = hi;

        // prefetch all 4 m-tile X fragments (b64 each)
        half4 xfr[4];
#pragma unroll
        for (int mt = 0; mt < 4; mt++)
            xfr[mt] = *(const half4*)(&rows[mt * 16 + n16][quad * 4]);

        // ---- 4 m-tiles of 16 samples each ----
#pragma unroll
        for (int mt = 0; mt < 4; mt++) {
            float4v acc[4];
#pragma unroll
            for (int nt = 0; nt < 4; nt++)
                acc[nt] = __builtin_amdgcn_mfma_f32_16x16x16f16(
                    w0f[nt], xfr[mt], zero4, 0, 0, 0);

            // lane holds y0[nt*16+4q+r] of sample n16 -> silu (packed f32
            // arith) -> scalar RTNE insert into phi-consistent L1 B-frag
            float4v s0 = acc[0] * sig4(acc[0]);
            float4v s1 = acc[1] * sig4(acc[1]);
            float4v s2 = acc[2] * sig4(acc[2]);
            float4v s3 = acc[3] * sig4(acc[3]);
            half8 h0, h1;
#pragma unroll
            for (int r = 0; r < 4; r++) {
                h0[r]     = (_Float16)s0[r];
                h0[4 + r] = (_Float16)s1[r];
                h1[r]     = (_Float16)s2[r];
                h1[4 + r] = (_Float16)s3[r];
            }

#pragma unroll
            for (int nt = 0; nt < 4; nt++) {
                float4v c = b1q[nt];
                c = __builtin_amdgcn_mfma_f32_16x16x32_f16(w1f[nt][0], h0, c, 0, 0, 0);
                c = __builtin_amdgcn_mfma_f32_16x16x32_f16(w1f[nt][1], h1, c, 0, 0, 0);
                acce[nt] += c * sig4(c);      // v_pk_fma_f32 pairs
            }
        }
    }

    // ---- deferred W2 dot (W2 only live after the loop), *ln2 once ----
    const float* W2 = is_atom ? aW2 : pW2;
    float4v dot4 = {0.f, 0.f, 0.f, 0.f};
#pragma unroll
    for (int nt = 0; nt < 4; nt++) {
        float4v w2v4 = *(const float4v*)(W2 + nt * 16 + quad * 4);
        dot4 += acce[nt] * w2v4;
    }
    float energy = (dot4[0] + dot4[1] + dot4[2] + dot4[3]) * LN2_F;

    // ---- block reduction -> one atomicAdd per block ----
#pragma unroll
    for (int off = 32; off > 0; off >>= 1)
        energy += __shfl_down(energy, off);
    __shared__ float wsum[4];
    if (lane == 0) wsum[wv] = energy;
    __syncthreads();
    if (tid == 0)
        atomicAdd(&out[b], wsum[0] + wsum[1] + wsum[2] + wsum[3]);
}

// ---------------------------------------------------------------------------
extern "C" void kernel_launch(void* const* d_in, const int* in_sizes, int n_in,
                              void* d_out, int out_size, void* d_ws, size_t ws_size,
                              hipStream_t stream) {
    const float* positions = (const float*)d_in[0];
    const int*   species   = (const int*)  d_in[1];
    const float* efield    = (const float*)d_in[2];
    const float* embed     = (const float*)d_in[3];
    const float* aW0 = (const float*)d_in[4];
    const float* ab0 = (const float*)d_in[5];
    const float* aW1 = (const float*)d_in[6];
    const float* ab1 = (const float*)d_in[7];
    const float* aW2 = (const float*)d_in[8];
    const float* ab2 = (const float*)d_in[9];
    const float* pW0 = (const float*)d_in[10];
    const float* pb0 = (const float*)d_in[11];
    const float* pW1 = (const float*)d_in[12];
    const float* pb1 = (const float*)d_in[13];
    const float* pW2 = (const float*)d_in[14];
    const float* pb2 = (const float*)d_in[15];
    float* outp = (float*)d_out;
    char*  ws   = (char*)d_ws;

    prep_kernel<<<dim3(5), dim3(256), 0, stream>>>(
        positions, embed, aW0, ab0, aW1, ab2, pW0, pb0, pW1, pb2, ws, outp);
    mlp_kernel<<<dim3(GRID_X, NBATCH), dim3(256), 0, stream>>>(
        positions, species, efield,
        ab1, aW2, pb1, pW2,
        ws, outp);
}

// Round 9
// 148.478 us; speedup vs baseline: 1.1585x; 1.0316x over previous
//
#include <hip/hip_runtime.h>

#define NA 1024
#define NBATCH 4
#define NPAIR 523776           // NA*(NA-1)/2
#define PAIR_TILES 2046        // NPAIR / 256
#define PAIR_BLOCKS 511        // pair blocks, strided tiles {bx, bx+511, ...}
#define GRID_X 512             // 511 pair + 1 atom block; 512*4 = 2048 blocks

#define LOG2E_F 1.44269504088896f
#define LN2_F   0.69314718055995f

// ws layout (byte offsets)
#define WS_MEAN 0              // 8 floats (per-batch mean x,y)
#define WS_W0P  64             // 1024 halves: pair W0eff frags (K=16, x log2e)
#define WS_W0A  2112           // 1024 halves: atom W0eff frags
#define WS_W1P  4160           // 4096 halves: pair W1 frags (phi-permuted rows)
#define WS_W1A  12352          // 4096 halves: atom W1 frags (phi-permuted rows)

typedef _Float16 half4 __attribute__((ext_vector_type(4)));
typedef _Float16 half8 __attribute__((ext_vector_type(8)));
typedef float float4v __attribute__((ext_vector_type(4)));

#if defined(__has_builtin)
#  if __has_builtin(__builtin_amdgcn_exp2f)
#    define EXP2F(x) __builtin_amdgcn_exp2f(x)
#  endif
#endif
#ifndef EXP2F
#  define EXP2F(x) exp2f(x)
#endif

// y = log2e * z.  sig4(y) = 1/(1+exp2(-y)) = sigmoid(z), elementwise on 4.
// Vector form so the non-trans ops lower to v_pk_add_f32 / v_pk_mul_f32 /
// v_pk_fma_f32 (packed fp32, 2 elems per issue) — trans ops stay scalar.
__device__ __forceinline__ float4v sig4(float4v y) {
    float4v e;
#pragma unroll
    for (int r = 0; r < 4; r++) e[r] = EXP2F(-y[r]);   // negate = free src mod
    float4v d = e + 1.0f;                              // v_pk_add_f32 x2
    float4v rr;
#pragma unroll
    for (int r = 0; r < 4; r++) rr[r] = __builtin_amdgcn_rcpf(d[r]);
    return rr;
}

__device__ __forceinline__ uint32_t pkf16(float a, float b) {
    union { _Float16 h[2]; uint32_t u; } x;
    x.h[0] = (_Float16)a; x.h[1] = (_Float16)b;   // RTNE
    return x.u;
}

// ---------------------------------------------------------------------------
// prep: blocks 0..3 -> per-batch mean + out[b] init; block 4 -> weight packing.
// W0eff (K=16, scaled by log2e): rows 0..4 = raw features, 5 = b0 (feature
// slot 5 == 1.0), 6..9 = one-hot(i) rows (embed@W0 folded), 10..13 =
// one-hot(j) rows (pair only), 14..15 = 0.
// K=16 frag order: [(nt*64+lane)*4 + j] = W[(lane>>4)*4+j][nt*16+(lane&15)]
//
// W1 frags phi-permuted so transposed-L0 output regs ARE the L1 B-fragment:
//   phi(ks*32+8q+j) = ks*32 + (j<4 ? 4q+j : 16+4q+j-4).
// W1 itself is NOT rescaled (ln2*log2e = 1); b1 gets *log2e at load; W2 *ln2.
// ---------------------------------------------------------------------------
__global__ void prep_kernel(const float* __restrict__ positions,
                            const float* __restrict__ embed,
                            const float* __restrict__ aW0,
                            const float* __restrict__ ab0,
                            const float* __restrict__ aW1,
                            const float* __restrict__ ab2,
                            const float* __restrict__ pW0,
                            const float* __restrict__ pb0,
                            const float* __restrict__ pW1,
                            const float* __restrict__ pb2,
                            char* __restrict__ ws,
                            float* __restrict__ out) {
    const int tid = threadIdx.x;
    if (blockIdx.x < 4) {
        const int b = blockIdx.x;
        const float2* pos = (const float2*)positions + b * NA;
        float sx = 0.f, sy = 0.f;
        for (int t = tid; t < NA; t += 256) {
            float2 p = pos[t];
            sx += p.x; sy += p.y;
        }
#pragma unroll
        for (int off = 32; off > 0; off >>= 1) {
            sx += __shfl_down(sx, off);
            sy += __shfl_down(sy, off);
        }
        __shared__ float rxs[4], rys[4];
        const int w = tid >> 6, lane = tid & 63;
        if (lane == 0) { rxs[w] = sx; rys[w] = sy; }
        __syncthreads();
        if (tid == 0) {
            float* meanws = (float*)(ws + WS_MEAN);
            meanws[b * 2 + 0] = (rxs[0] + rxs[1] + rxs[2] + rxs[3]) * (1.f / NA);
            meanws[b * 2 + 1] = (rys[0] + rys[1] + rys[2] + rys[3]) * (1.f / NA);
            out[b] = (float)NPAIR * pb2[0] + (float)NA * ab2[0];
        }
        return;
    }

    // ---- weight fragment packing ----
    _Float16* w0p = (_Float16*)(ws + WS_W0P);
    _Float16* w0a = (_Float16*)(ws + WS_W0A);
    _Float16* w1p = (_Float16*)(ws + WS_W1P);
    _Float16* w1a = (_Float16*)(ws + WS_W1A);

    for (int idx = tid; idx < 1024; idx += 256) {
        const int j = idx & 3, lane = (idx >> 2) & 63, nt = idx >> 8;
        const int k = ((lane >> 4) << 2) + j;      // 4q + j, 0..15
        const int col = nt * 16 + (lane & 15);
        float vp = 0.f, va = 0.f;
        if (k < 5) {
            vp = pW0[k * 64 + col];
            va = aW0[k * 64 + col];
        } else if (k == 5) {               // bias row (feature slot 5 == 1.0)
            vp = pb0[col];
            va = ab0[col];
        } else if (k >= 6 && k <= 9) {
            const int s = k - 6;
            float accp = 0.f, acca = 0.f;
#pragma unroll
            for (int e = 0; e < 16; e++) {
                float em = embed[s * 16 + e];
                accp += em * pW0[(5 + e) * 64 + col];
                acca += em * aW0[(5 + e) * 64 + col];
            }
            vp = accp; va = acca;
        } else if (k >= 10 && k <= 13) {
            const int s = k - 10;
            float accp = 0.f;
#pragma unroll
            for (int e = 0; e < 16; e++)
                accp += embed[s * 16 + e] * pW0[(21 + e) * 64 + col];
            vp = accp; va = 0.f;
        }
        w0p[idx] = (_Float16)(vp * LOG2E_F);
        w0a[idx] = (_Float16)(va * LOG2E_F);
    }
    for (int idx = tid; idx < 4096; idx += 256) {
        const int j = idx & 7, lane = (idx >> 3) & 63;
        const int ks = (idx >> 9) & 1, nt = idx >> 10;
        const int q = lane >> 4;
        // phi row permutation: slot (q,j) sources hidden 4q+j (j<4) / 16+4q+j-4
        const int m = (j < 4) ? (4 * q + j) : (16 + 4 * q + (j - 4));
        const int k = ks * 32 + m;
        const int col = nt * 16 + (lane & 15);
        w1p[idx] = (_Float16)pW1[k * 64 + col];
        w1a[idx] = (_Float16)aW1[k * 64 + col];
    }
}

// ---------------------------------------------------------------------------
// fused pair+atom MLP, transposed dataflow, log2e-folded silu chain:
//   L0 (K=16): acc = mfma_16x16x16(W0frag, Xfrag) -> y0 = log2e*z0
//   h' = y0*sig4(y0) = log2e*silu(z0), packed into the phi-consistent L1
//   B-fragment (no LDS round-trip).
//   L1 (K=64): c = mfma_16x16x32(W1frag, h) + b1*log2e -> y1 = log2e*z1
//   acce += c*sig4(c) (v_pk_fma); after the t-loop: energy = ln2*dot(acce,W2).
//
// EXACT restore of the best verified configuration (R3: 67.3 us mlp, clean
// counters). Session forensics — all of the following were tried and REGRESS
// via per-thread scratch at the 64-VGPR operating point the backend pins this
// kernel to (any added live state or scheduling freedom spills, it never
// allocates reg #65):
//   - waves_per_eu(4,4)              -> 2.1 MB scratch writes (R2)
//   - cvt_pkrtz pack, union form     -> 6.2 MB (R5)
//   - cvt_pkrtz pack, shufflevector  -> 6.2 MB (R6)
//   - cross-tile software pipeline   -> 75 MB (R7)
//   - closed-form decode + hoisted invariant packs -> 6.2 MB (R8; the while
//     loops below act as a scheduling barrier keeping live ranges short)
// Keep: while-loop decode, per-tile pkf16 packs, scalar RTNE h-pack inserts,
// __launch_bounds__(256,4), sequential t-loop.
// ---------------------------------------------------------------------------
__global__ __launch_bounds__(256, 4) void mlp_kernel(
    const float* __restrict__ positions,
    const int*   __restrict__ species,
    const float* __restrict__ efield,
    const float* __restrict__ ab1, const float* __restrict__ aW2,
    const float* __restrict__ pb1, const float* __restrict__ pW2,
    const char*  __restrict__ ws,
    float* __restrict__ out)
{
    const int b    = blockIdx.y;
    const int bx   = blockIdx.x;
    const bool is_atom = (bx == PAIR_BLOCKS);
    const int tid  = threadIdx.x;
    const int lane = tid & 63;
    const int wv   = tid >> 6;
    const int n16  = lane & 15;
    const int quad = lane >> 4;

    // X staging: 64 rows x 24 halves per wave (cols 0..15 live, 16..23 pad).
    // 48B row stride: conflict-free for both b128 writes and b64 reads.
    __shared__ __attribute__((aligned(16))) _Float16 Xbuf[4][64][24];
    _Float16 (*rows)[24] = Xbuf[wv];

    // ---- block-wide weight fragments (coalesced, once per block) ----
    const _Float16* w0w = (const _Float16*)(ws + (is_atom ? WS_W0A : WS_W0P));
    const _Float16* w1w = (const _Float16*)(ws + (is_atom ? WS_W1A : WS_W1P));
    half4 w0f[4];
    half8 w1f[4][2];
#pragma unroll
    for (int nt = 0; nt < 4; nt++)
        w0f[nt] = *(const half4*)(w0w + (nt * 64 + lane) * 4);
#pragma unroll
    for (int nt = 0; nt < 4; nt++)
#pragma unroll
        for (int ks = 0; ks < 2; ks++)
            w1f[nt][ks] = *(const half8*)(w1w + ((nt * 2 + ks) * 64 + lane) * 8);

    const float* B1 = is_atom ? ab1 : pb1;
    float4v b1q[4];
#pragma unroll
    for (int nt = 0; nt < 4; nt++) {
        float4v t4 = *(const float4v*)(B1 + nt * 16 + quad * 4);  // rows quad*4+r
        b1q[nt] = t4 * LOG2E_F;
    }

    const float Ex = efield[b * 2 + 0];
    const float Ey = efield[b * 2 + 1];
    const float enorm = sqrtf(Ex * Ex + Ey * Ey);
    const float* meanws = (const float*)(ws + WS_MEAN);

    // blocks 0,1 take a 5th tile (2046 = 511*4 + 2)
    const int my_tiles = is_atom ? 4 : ((bx < PAIR_TILES - 4 * PAIR_BLOCKS) ? 5 : 4);

    const float4v zero4 = {0.f, 0.f, 0.f, 0.f};
    float4v acce[4];
#pragma unroll
    for (int nt = 0; nt < 4; nt++) acce[nt] = zero4;

    for (int t = 0; t < my_tiles; ++t) {
        // ---- build feature row (14 live halves of K=16, slot5 = 1.0) ----
        uint32_t w01, w23;
        uint64_t ohi, ohj;
        if (!is_atom) {
            const int tile = bx + t * PAIR_BLOCKS;
            const int p = tile * 256 + tid;
            float Df = (float)(2047 * 2047 - 8 * p);
            int i = (int)((2047.0f - sqrtf(Df)) * 0.5f);
            i = i < 0 ? 0 : (i > 1022 ? 1022 : i);
            while (i * (2047 - i) / 2 > p) --i;
            while ((i + 1) * (2046 - i) / 2 <= p) ++i;
            const int j = p - i * (2047 - i) / 2 + i + 1;
            const float2* pos = (const float2*)positions + b * NA;
            float2 pi = pos[i], pj = pos[j];
            float f0 = pi.x - pj.x, f1 = pi.y - pj.y;     // mean cancels
            float f2 = sqrtf(f0 * f0 + f1 * f1);
            float inv = __builtin_amdgcn_rcpf(fmaxf(f2, 1e-12f));
            float f3 = (Ex * f0 + Ey * f1) * inv;
            w01 = pkf16(f0, f1);
            w23 = pkf16(f2, f3);
            ohi = 0x3C00ull << (species[b * NA + i] * 16);
            ohj = 0x3C00ull << (species[b * NA + j] * 16);
        } else {
            const int n = t * 256 + tid;
            float2 pn = ((const float2*)positions)[b * NA + n];
            w01 = pkf16(pn.x - meanws[b * 2 + 0], pn.y - meanws[b * 2 + 1]);
            w23 = pkf16(Ex, Ey);
            ohi = 0x3C00ull << (species[b * NA + n] * 16);
            ohj = 0;
        }
        // halves: 0..4 = f0..f4(enorm), 5 = 1.0 (bias), 6..9 = oh_i, 10..13 = oh_j
        int4* dst = (int4*)&rows[lane][0];
        int4 lo, hi;
        lo.x = (int)w01;
        lo.y = (int)w23;
        lo.z = (int)pkf16(enorm, 1.0f);
        lo.w = (int)(uint32_t)ohi;
        hi.x = (int)(uint32_t)(ohi >> 32);
        hi.y = (int)(uint32_t)ohj;
        hi.z = (int)(uint32_t)(ohj >> 32);
        hi.w = 0;
        dst[0] = lo;
        dst[1] = hi;

        // prefetch all 4 m-tile X fragments (b64 each)
        half4 xfr[4];
#pragma unroll
        for (int mt = 0; mt < 4; mt++)
            xfr[mt] = *(const half4*)(&rows[mt * 16 + n16][quad * 4]);

        // ---- 4 m-tiles of 16 samples each ----
#pragma unroll
        for (int mt = 0; mt < 4; mt++) {
            float4v acc[4];
#pragma unroll
            for (int nt = 0; nt < 4; nt++)
                acc[nt] = __builtin_amdgcn_mfma_f32_16x16x16f16(
                    w0f[nt], xfr[mt], zero4, 0, 0, 0);

            // lane holds y0[nt*16+4q+r] of sample n16 -> silu (packed f32
            // arith) -> scalar RTNE insert into phi-consistent L1 B-frag
            float4v s0 = acc[0] * sig4(acc[0]);
            float4v s1 = acc[1] * sig4(acc[1]);
            float4v s2 = acc[2] * sig4(acc[2]);
            float4v s3 = acc[3] * sig4(acc[3]);
            half8 h0, h1;
#pragma unroll
            for (int r = 0; r < 4; r++) {
                h0[r]     = (_Float16)s0[r];
                h0[4 + r] = (_Float16)s1[r];
                h1[r]     = (_Float16)s2[r];
                h1[4 + r] = (_Float16)s3[r];
            }

#pragma unroll
            for (int nt = 0; nt < 4; nt++) {
                float4v c = b1q[nt];
                c = __builtin_amdgcn_mfma_f32_16x16x32_f16(w1f[nt][0], h0, c, 0, 0, 0);
                c = __builtin_amdgcn_mfma_f32_16x16x32_f16(w1f[nt][1], h1, c, 0, 0, 0);
                acce[nt] += c * sig4(c);      // v_pk_fma_f32 pairs
            }
        }
    }

    // ---- deferred W2 dot (W2 only live after the loop), *ln2 once ----
    const float* W2 = is_atom ? aW2 : pW2;
    float4v dot4 = {0.f, 0.f, 0.f, 0.f};
#pragma unroll
    for (int nt = 0; nt < 4; nt++) {
        float4v w2v4 = *(const float4v*)(W2 + nt * 16 + quad * 4);
        dot4 += acce[nt] * w2v4;
    }
    float energy = (dot4[0] + dot4[1] + dot4[2] + dot4[3]) * LN2_F;

    // ---- block reduction -> one atomicAdd per block ----
#pragma unroll
    for (int off = 32; off > 0; off >>= 1)
        energy += __shfl_down(energy, off);
    __shared__ float wsum[4];
    if (lane == 0) wsum[wv] = energy;
    __syncthreads();
    if (tid == 0)
        atomicAdd(&out[b], wsum[0] + wsum[1] + wsum[2] + wsum[3]);
}

// ---------------------------------------------------------------------------
extern "C" void kernel_launch(void* const* d_in, const int* in_sizes, int n_in,
                              void* d_out, int out_size, void* d_ws, size_t ws_size,
                              hipStream_t stream) {
    const float* positions = (const float*)d_in[0];
    const int*   species   = (const int*)  d_in[1];
    const float* efield    = (const float*)d_in[2];
    const float* embed     = (const float*)d_in[3];
    const float* aW0 = (const float*)d_in[4];
    const float* ab0 = (const float*)d_in[5];
    const float* aW1 = (const float*)d_in[6];
    const float* ab1 = (const float*)d_in[7];
    const float* aW2 = (const float*)d_in[8];
    const float* ab2 = (const float*)d_in[9];
    const float* pW0 = (const float*)d_in[10];
    const float* pb0 = (const float*)d_in[11];
    const float* pW1 = (const float*)d_in[12];
    const float* pb1 = (const float*)d_in[13];
    const float* pW2 = (const float*)d_in[14];
    const float* pb2 = (const float*)d_in[15];
    float* outp = (float*)d_out;
    char*  ws   = (char*)d_ws;

    prep_kernel<<<dim3(5), dim3(256), 0, stream>>>(
        positions, embed, aW0, ab0, aW1, ab2, pW0, pb0, pW1, pb2, ws, outp);
    mlp_kernel<<<dim3(GRID_X, NBATCH), dim3(256), 0, stream>>>(
        positions, species, efield,
        ab1, aW2, pb1, pW2,
        ws, outp);
}

// Round 10
// 146.126 us; speedup vs baseline: 1.1771x; 1.0161x over previous
//
#include <hip/hip_runtime.h>

#define NA 1024
#define NBATCH 4
#define NPAIR 523776           // NA*(NA-1)/2
#define PAIR_TILES 2046        // NPAIR / 256
#define PAIR_BLOCKS 511        // pair blocks, strided tiles {bx, bx+511, ...}
#define GRID_X 512             // 511 pair + 1 atom block; 512*4 = 2048 blocks

#define LOG2E_F 1.44269504088896f
#define LN2_F   0.69314718055995f

// ws layout (byte offsets)
#define WS_MEAN 0              // 8 floats (per-batch mean x,y)
#define WS_W0P  64             // 1024 halves: pair W0eff frags (K=16, x log2e)
#define WS_W0A  2112           // 1024 halves: atom W0eff frags
#define WS_W1P  4160           // 4096 halves: pair W1 frags (phi-permuted rows)
#define WS_W1A  12352          // 4096 halves: atom W1 frags (phi-permuted rows)

typedef _Float16 half4 __attribute__((ext_vector_type(4)));
typedef _Float16 half8 __attribute__((ext_vector_type(8)));
typedef float float4v __attribute__((ext_vector_type(4)));

#if defined(__has_builtin)
#  if __has_builtin(__builtin_amdgcn_exp2f)
#    define EXP2F(x) __builtin_amdgcn_exp2f(x)
#  endif
#endif
#ifndef EXP2F
#  define EXP2F(x) exp2f(x)
#endif

// y = log2e * z.  sig4(y) = 1/(1+exp2(-y)) = sigmoid(z), elementwise on 4.
// Vector form so the non-trans ops lower to v_pk_add_f32 / v_pk_mul_f32 /
// v_pk_fma_f32 (packed fp32, 2 elems per issue) — trans ops stay scalar.
__device__ __forceinline__ float4v sig4(float4v y) {
    float4v e;
#pragma unroll
    for (int r = 0; r < 4; r++) e[r] = EXP2F(-y[r]);   // negate = free src mod
    float4v d = e + 1.0f;                              // v_pk_add_f32 x2
    float4v rr;
#pragma unroll
    for (int r = 0; r < 4; r++) rr[r] = __builtin_amdgcn_rcpf(d[r]);
    return rr;
}

__device__ __forceinline__ uint32_t pkf16(float a, float b) {
    union { _Float16 h[2]; uint32_t u; } x;
    x.h[0] = (_Float16)a; x.h[1] = (_Float16)b;   // RTNE
    return x.u;
}

// ---------------------------------------------------------------------------
// prep: blocks 0..3 -> per-batch mean + out[b] init; block 4 -> weight packing.
// W0eff (K=16, scaled by log2e): rows 0..4 = raw features, 5 = b0 (feature
// slot 5 == 1.0), 6..9 = one-hot(i) rows (embed@W0 folded), 10..13 =
// one-hot(j) rows (pair only), 14..15 = 0.
// K=16 frag order: [(nt*64+lane)*4 + j] = W[(lane>>4)*4+j][nt*16+(lane&15)]
//
// W1 frags phi-permuted so transposed-L0 output regs ARE the L1 B-fragment:
//   phi(ks*32+8q+j) = ks*32 + (j<4 ? 4q+j : 16+4q+j-4).
// W1 itself is NOT rescaled (ln2*log2e = 1); b1 gets *log2e at load; W2 *ln2.
// ---------------------------------------------------------------------------
__global__ void prep_kernel(const float* __restrict__ positions,
                            const float* __restrict__ embed,
                            const float* __restrict__ aW0,
                            const float* __restrict__ ab0,
                            const float* __restrict__ aW1,
                            const float* __restrict__ ab2,
                            const float* __restrict__ pW0,
                            const float* __restrict__ pb0,
                            const float* __restrict__ pW1,
                            const float* __restrict__ pb2,
                            char* __restrict__ ws,
                            float* __restrict__ out) {
    const int tid = threadIdx.x;
    if (blockIdx.x < 4) {
        const int b = blockIdx.x;
        const float2* pos = (const float2*)positions + b * NA;
        float sx = 0.f, sy = 0.f;
        for (int t = tid; t < NA; t += 256) {
            float2 p = pos[t];
            sx += p.x; sy += p.y;
        }
#pragma unroll
        for (int off = 32; off > 0; off >>= 1) {
            sx += __shfl_down(sx, off);
            sy += __shfl_down(sy, off);
        }
        __shared__ float rxs[4], rys[4];
        const int w = tid >> 6, lane = tid & 63;
        if (lane == 0) { rxs[w] = sx; rys[w] = sy; }
        __syncthreads();
        if (tid == 0) {
            float* meanws = (float*)(ws + WS_MEAN);
            meanws[b * 2 + 0] = (rxs[0] + rxs[1] + rxs[2] + rxs[3]) * (1.f / NA);
            meanws[b * 2 + 1] = (rys[0] + rys[1] + rys[2] + rys[3]) * (1.f / NA);
            out[b] = (float)NPAIR * pb2[0] + (float)NA * ab2[0];
        }
        return;
    }

    // ---- weight fragment packing ----
    _Float16* w0p = (_Float16*)(ws + WS_W0P);
    _Float16* w0a = (_Float16*)(ws + WS_W0A);
    _Float16* w1p = (_Float16*)(ws + WS_W1P);
    _Float16* w1a = (_Float16*)(ws + WS_W1A);

    for (int idx = tid; idx < 1024; idx += 256) {
        const int j = idx & 3, lane = (idx >> 2) & 63, nt = idx >> 8;
        const int k = ((lane >> 4) << 2) + j;      // 4q + j, 0..15
        const int col = nt * 16 + (lane & 15);
        float vp = 0.f, va = 0.f;
        if (k < 5) {
            vp = pW0[k * 64 + col];
            va = aW0[k * 64 + col];
        } else if (k == 5) {               // bias row (feature slot 5 == 1.0)
            vp = pb0[col];
            va = ab0[col];
        } else if (k >= 6 && k <= 9) {
            const int s = k - 6;
            float accp = 0.f, acca = 0.f;
#pragma unroll
            for (int e = 0; e < 16; e++) {
                float em = embed[s * 16 + e];
                accp += em * pW0[(5 + e) * 64 + col];
                acca += em * aW0[(5 + e) * 64 + col];
            }
            vp = accp; va = acca;
        } else if (k >= 10 && k <= 13) {
            const int s = k - 10;
            float accp = 0.f;
#pragma unroll
            for (int e = 0; e < 16; e++)
                accp += embed[s * 16 + e] * pW0[(21 + e) * 64 + col];
            vp = accp; va = 0.f;
        }
        w0p[idx] = (_Float16)(vp * LOG2E_F);
        w0a[idx] = (_Float16)(va * LOG2E_F);
    }
    for (int idx = tid; idx < 4096; idx += 256) {
        const int j = idx & 7, lane = (idx >> 3) & 63;
        const int ks = (idx >> 9) & 1, nt = idx >> 10;
        const int q = lane >> 4;
        // phi row permutation: slot (q,j) sources hidden 4q+j (j<4) / 16+4q+j-4
        const int m = (j < 4) ? (4 * q + j) : (16 + 4 * q + (j - 4));
        const int k = ks * 32 + m;
        const int col = nt * 16 + (lane & 15);
        w1p[idx] = (_Float16)pW1[k * 64 + col];
        w1a[idx] = (_Float16)aW1[k * 64 + col];
    }
}

// ---------------------------------------------------------------------------
// fused pair+atom MLP, transposed dataflow, log2e-folded silu chain:
//   L0 (K=16): acc = mfma_16x16x16(W0frag, Xfrag) -> y0 = log2e*z0
//   h' = y0*sig4(y0) = log2e*silu(z0), packed into the phi-consistent L1
//   B-fragment (no LDS round-trip).
//   L1 (K=64): c = mfma_16x16x32(W1frag, h) + b1*log2e -> y1 = log2e*z1
//   acce += c*sig4(c) (v_pk_fma); after the t-loop: energy = ln2*dot(acce,W2).
//
// TERMINAL KERNEL — exact restore of the best verified codegen shape (R3:
// 67.3 us mlp, WRITE 64 KB). The exact source shape matters: f0..f3/ohi/ohj
// declared BEFORE the branch, all pkf16 packs AFTER it, while-loop decode.
// Session forensics — everything below regressed via per-thread scratch at
// the 64-VGPR operating point the backend pins this kernel to (it spills
// rather than allocating reg #65):
//   - waves_per_eu(4,4)                      -> 2.1 MB scratch (R2)
//   - cvt_pkrtz pack (union / shufflevector) -> 6.2 MB (R5/R6)
//   - cross-tile software pipeline           -> 75 MB (R7)
//   - closed-form decode + hoisted packs     -> 6.2 MB (R8)
//   - packs moved inside branches            -> 2.1 MB (R9)
// Residual structure: ~51 us VALU-issue floor (62% of it transcendental
// silu, irreducible) + ~25% dependency idle reachable only by adding live
// state, which this regalloc wall forbids at HIP source level.
// ---------------------------------------------------------------------------
__global__ __launch_bounds__(256, 4) void mlp_kernel(
    const float* __restrict__ positions,
    const int*   __restrict__ species,
    const float* __restrict__ efield,
    const float* __restrict__ ab1, const float* __restrict__ aW2,
    const float* __restrict__ pb1, const float* __restrict__ pW2,
    const char*  __restrict__ ws,
    float* __restrict__ out)
{
    const int b    = blockIdx.y;
    const int bx   = blockIdx.x;
    const bool is_atom = (bx == PAIR_BLOCKS);
    const int tid  = threadIdx.x;
    const int lane = tid & 63;
    const int wv   = tid >> 6;
    const int n16  = lane & 15;
    const int quad = lane >> 4;

    // X staging: 64 rows x 24 halves per wave (cols 0..15 live, 16..23 pad).
    // 48B row stride: conflict-free for both b128 writes and b64 reads.
    __shared__ __attribute__((aligned(16))) _Float16 Xbuf[4][64][24];
    _Float16 (*rows)[24] = Xbuf[wv];

    // ---- block-wide weight fragments (coalesced, once per block) ----
    const _Float16* w0w = (const _Float16*)(ws + (is_atom ? WS_W0A : WS_W0P));
    const _Float16* w1w = (const _Float16*)(ws + (is_atom ? WS_W1A : WS_W1P));
    half4 w0f[4];
    half8 w1f[4][2];
#pragma unroll
    for (int nt = 0; nt < 4; nt++)
        w0f[nt] = *(const half4*)(w0w + (nt * 64 + lane) * 4);
#pragma unroll
    for (int nt = 0; nt < 4; nt++)
#pragma unroll
        for (int ks = 0; ks < 2; ks++)
            w1f[nt][ks] = *(const half8*)(w1w + ((nt * 2 + ks) * 64 + lane) * 8);

    const float* B1 = is_atom ? ab1 : pb1;
    float4v b1q[4];
#pragma unroll
    for (int nt = 0; nt < 4; nt++) {
        float4v t4 = *(const float4v*)(B1 + nt * 16 + quad * 4);  // rows quad*4+r
        b1q[nt] = t4 * LOG2E_F;
    }

    const float Ex = efield[b * 2 + 0];
    const float Ey = efield[b * 2 + 1];
    const float enorm = sqrtf(Ex * Ex + Ey * Ey);
    const float* meanws = (const float*)(ws + WS_MEAN);

    // blocks 0,1 take a 5th tile (2046 = 511*4 + 2)
    const int my_tiles = is_atom ? 4 : ((bx < PAIR_TILES - 4 * PAIR_BLOCKS) ? 5 : 4);

    const float4v zero4 = {0.f, 0.f, 0.f, 0.f};
    float4v acce[4];
#pragma unroll
    for (int nt = 0; nt < 4; nt++) acce[nt] = zero4;

    for (int t = 0; t < my_tiles; ++t) {
        // ---- build feature row (14 live halves of K=16, slot5 = 1.0) ----
        float f0, f1, f2, f3;
        uint64_t ohi, ohj;
        if (!is_atom) {
            const int tile = bx + t * PAIR_BLOCKS;
            const int p = tile * 256 + tid;
            float Df = (float)(2047 * 2047 - 8 * p);
            int i = (int)((2047.0f - sqrtf(Df)) * 0.5f);
            i = i < 0 ? 0 : (i > 1022 ? 1022 : i);
            while (i * (2047 - i) / 2 > p) --i;
            while ((i + 1) * (2046 - i) / 2 <= p) ++i;
            const int j = p - i * (2047 - i) / 2 + i + 1;
            const float2* pos = (const float2*)positions + b * NA;
            float2 pi = pos[i], pj = pos[j];
            f0 = pi.x - pj.x; f1 = pi.y - pj.y;           // mean cancels
            f2 = sqrtf(f0 * f0 + f1 * f1);
            float inv = __builtin_amdgcn_rcpf(fmaxf(f2, 1e-12f));
            f3 = (Ex * f0 + Ey * f1) * inv;
            ohi = 0x3C00ull << (species[b * NA + i] * 16);
            ohj = 0x3C00ull << (species[b * NA + j] * 16);
        } else {
            const int n = t * 256 + tid;
            float2 pn = ((const float2*)positions)[b * NA + n];
            f0 = pn.x - meanws[b * 2 + 0];
            f1 = pn.y - meanws[b * 2 + 1];
            f2 = Ex; f3 = Ey;
            ohi = 0x3C00ull << (species[b * NA + n] * 16);
            ohj = 0;
        }
        // halves: 0..4 = f0..f4(enorm), 5 = 1.0 (bias), 6..9 = oh_i, 10..13 = oh_j
        int4* dst = (int4*)&rows[lane][0];
        int4 lo, hi;
        lo.x = (int)pkf16(f0, f1);
        lo.y = (int)pkf16(f2, f3);
        lo.z = (int)pkf16(enorm, 1.0f);
        lo.w = (int)(uint32_t)ohi;
        hi.x = (int)(uint32_t)(ohi >> 32);
        hi.y = (int)(uint32_t)ohj;
        hi.z = (int)(uint32_t)(ohj >> 32);
        hi.w = 0;
        dst[0] = lo;
        dst[1] = hi;

        // prefetch all 4 m-tile X fragments (b64 each)
        half4 xfr[4];
#pragma unroll
        for (int mt = 0; mt < 4; mt++)
            xfr[mt] = *(const half4*)(&rows[mt * 16 + n16][quad * 4]);

        // ---- 4 m-tiles of 16 samples each ----
#pragma unroll
        for (int mt = 0; mt < 4; mt++) {
            float4v acc[4];
#pragma unroll
            for (int nt = 0; nt < 4; nt++)
                acc[nt] = __builtin_amdgcn_mfma_f32_16x16x16f16(
                    w0f[nt], xfr[mt], zero4, 0, 0, 0);

            // lane holds y0[nt*16+4q+r] of sample n16 -> silu (packed f32
            // arith) -> scalar RTNE insert into phi-consistent L1 B-frag
            float4v s0 = acc[0] * sig4(acc[0]);
            float4v s1 = acc[1] * sig4(acc[1]);
            float4v s2 = acc[2] * sig4(acc[2]);
            float4v s3 = acc[3] * sig4(acc[3]);
            half8 h0, h1;
#pragma unroll
            for (int r = 0; r < 4; r++) {
                h0[r]     = (_Float16)s0[r];
                h0[4 + r] = (_Float16)s1[r];
                h1[r]     = (_Float16)s2[r];
                h1[4 + r] = (_Float16)s3[r];
            }

#pragma unroll
            for (int nt = 0; nt < 4; nt++) {
                float4v c = b1q[nt];
                c = __builtin_amdgcn_mfma_f32_16x16x32_f16(w1f[nt][0], h0, c, 0, 0, 0);
                c = __builtin_amdgcn_mfma_f32_16x16x32_f16(w1f[nt][1], h1, c, 0, 0, 0);
                acce[nt] += c * sig4(c);      // v_pk_fma_f32 pairs
            }
        }
    }

    // ---- deferred W2 dot (W2 only live after the loop), *ln2 once ----
    const float* W2 = is_atom ? aW2 : pW2;
    float4v dot4 = {0.f, 0.f, 0.f, 0.f};
#pragma unroll
    for (int nt = 0; nt < 4; nt++) {
        float4v w2v4 = *(const float4v*)(W2 + nt * 16 + quad * 4);
        dot4 += acce[nt] * w2v4;
    }
    float energy = (dot4[0] + dot4[1] + dot4[2] + dot4[3]) * LN2_F;

    // ---- block reduction -> one atomicAdd per block ----
#pragma unroll
    for (int off = 32; off > 0; off >>= 1)
        energy += __shfl_down(energy, off);
    __shared__ float wsum[4];
    if (lane == 0) wsum[wv] = energy;
    __syncthreads();
    if (tid == 0)
        atomicAdd(&out[b], wsum[0] + wsum[1] + wsum[2] + wsum[3]);
}

// ---------------------------------------------------------------------------
extern "C" void kernel_launch(void* const* d_in, const int* in_sizes, int n_in,
                              void* d_out, int out_size, void* d_ws, size_t ws_size,
                              hipStream_t stream) {
    const float* positions = (const float*)d_in[0];
    const int*   species   = (const int*)  d_in[1];
    const float* efield    = (const float*)d_in[2];
    const float* embed     = (const float*)d_in[3];
    const float* aW0 = (const float*)d_in[4];
    const float* ab0 = (const float*)d_in[5];
    const float* aW1 = (const float*)d_in[6];
    const float* ab1 = (const float*)d_in[7];
    const float* aW2 = (const float*)d_in[8];
    const float* ab2 = (const float*)d_in[9];
    const float* pW0 = (const float*)d_in[10];
    const float* pb0 = (const float*)d_in[11];
    const float* pW1 = (const float*)d_in[12];
    const float* pb1 = (const float*)d_in[13];
    const float* pW2 = (const float*)d_in[14];
    const float* pb2 = (const float*)d_in[15];
    float* outp = (float*)d_out;
    char*  ws   = (char*)d_ws;

    prep_kernel<<<dim3(5), dim3(256), 0, stream>>>(
        positions, embed, aW0, ab0, aW1, ab2, pW0, pb0, pW1, pb2, ws, outp);
    mlp_kernel<<<dim3(GRID_X, NBATCH), dim3(256), 0, stream>>>(
        positions, species, efield,
        ab1, aW2, pb1, pW2,
        ws, outp);
}